// Round 3
// baseline (344.667 us; speedup 1.0000x reference)
//
#include <hip/hip_runtime.h>
#include <math.h>

#define L_SEQ 1024
#define DMODEL 512
#define NHEAD 8
#define NB 2
#define LP 1028   // padded LDS row stride (floats); 1028%32==4 -> verified <=2-way banks

typedef __attribute__((ext_vector_type(8))) short bf8;
typedef __attribute__((ext_vector_type(4))) float f4;

__device__ __forceinline__ short f2bf(float f) {
    unsigned u = __float_as_uint(f);
    unsigned r = u + 0x7FFF + ((u >> 16) & 1);   // round-to-nearest-even
    return (short)(r >> 16);
}

// ---------------------------------------------------------------------------
// fp32 -> bf16 cast for q,k,v in one dispatch (blockIdx.y selects array)
// ---------------------------------------------------------------------------
__global__ __launch_bounds__(256) void cast3_bf16_kernel(
    const float* __restrict__ q, const float* __restrict__ k,
    const float* __restrict__ v,
    short* __restrict__ qb, short* __restrict__ kb, short* __restrict__ vb)
{
    const float* src = (blockIdx.y == 0) ? q : (blockIdx.y == 1) ? k : v;
    short* dst = (blockIdx.y == 0) ? qb : (blockIdx.y == 1) ? kb : vb;
    int i = blockIdx.x * 256 + threadIdx.x;
    float4 f = ((const float4*)src)[i];
    short4 o;
    o.x = f2bf(f.x); o.y = f2bf(f.y); o.z = f2bf(f.z); o.w = f2bf(f.w);
    ((short4*)dst)[i] = o;
}

// ---------------------------------------------------------------------------
// 512x512 fp32 W[k][n] -> bf16 Wt[n][k], 4 matrices via blockIdx.z
// ---------------------------------------------------------------------------
__global__ __launch_bounds__(256) void transpose_cast_kernel(
    const float* __restrict__ s0, const float* __restrict__ s1,
    const float* __restrict__ s2, const float* __restrict__ s3,
    short* __restrict__ d0, short* __restrict__ d1,
    short* __restrict__ d2, short* __restrict__ d3)
{
    const float* src; short* dst;
    switch (blockIdx.z) {
        case 0: src = s0; dst = d0; break;
        case 1: src = s1; dst = d1; break;
        case 2: src = s2; dst = d2; break;
        default: src = s3; dst = d3; break;
    }
    __shared__ float tile[32][33];
    const int tx = threadIdx.x, ty = threadIdx.y;
    const int x0 = blockIdx.x * 32, y0 = blockIdx.y * 32;
#pragma unroll
    for (int j = 0; j < 32; j += 8)
        tile[ty + j][tx] = src[(size_t)(y0 + ty + j) * 512 + x0 + tx];
    __syncthreads();
#pragma unroll
    for (int j = 0; j < 32; j += 8)
        dst[(size_t)(x0 + ty + j) * 512 + y0 + tx] = f2bf(tile[tx][ty + j]);
}

// ---------------------------------------------------------------------------
// MFMA GEMM body: C[m,n] = sum_k A[m,k]*Bt[n,k] + bias[n]
// 64m x 64n tile, 4 waves (wave = 16 rows, 4 n-frags), K=512.
// mode 0: bf16 natural [m][n]; mode 1: bf16 transposed [b][n][l]; mode 2: fp32.
// ---------------------------------------------------------------------------
__device__ __forceinline__ void gemm_mfma_body(
    const short* __restrict__ A, const short* __restrict__ Bt,
    const float* __restrict__ bias, void* __restrict__ Cout, int mode)
{
    const int w = threadIdx.x >> 6, lane = threadIdx.x & 63;
    const int lr = lane & 15, lq = lane >> 4;
    const int m_base = blockIdx.y * 64 + w * 16;
    const int n_base = blockIdx.x * 64;

    f4 acc[4];
    const f4 zero = {0.f, 0.f, 0.f, 0.f};
#pragma unroll
    for (int nf = 0; nf < 4; ++nf) acc[nf] = zero;

    for (int k0 = 0; k0 < 512; k0 += 32) {
        bf8 a = *(const bf8*)(A + (size_t)(m_base + lr) * 512 + k0 + lq * 8);
#pragma unroll
        for (int nf = 0; nf < 4; ++nf) {
            bf8 b = *(const bf8*)(Bt + (size_t)(n_base + nf * 16 + lr) * 512 + k0 + lq * 8);
            acc[nf] = __builtin_amdgcn_mfma_f32_16x16x32_bf16(a, b, acc[nf], 0, 0, 0);
        }
    }

#pragma unroll
    for (int nf = 0; nf < 4; ++nf) {
        const int n = n_base + nf * 16 + lr;
        const float bv = bias[n];
        const int mrow = m_base + lq * 4;
#pragma unroll
        for (int r = 0; r < 4; ++r) {
            const float val = acc[nf][r] + bv;
            const int m = mrow + r;
            if (mode == 0) {
                ((short*)Cout)[(size_t)m * 512 + n] = f2bf(val);
            } else if (mode == 1) {
                const int bb = m >> 10, l = m & 1023;
                ((short*)Cout)[((size_t)bb * 512 + n) * 1024 + l] = f2bf(val);
            } else {
                ((float*)Cout)[(size_t)m * 512 + n] = val;
            }
        }
    }
}

// QKV projections in one dispatch: blockIdx.z selects which
__global__ __launch_bounds__(256) void qkv_proj_kernel(
    const short* __restrict__ qb, const short* __restrict__ kb,
    const short* __restrict__ vb,
    const short* __restrict__ Wtq, const short* __restrict__ Wtk,
    const short* __restrict__ Wtv,
    const float* __restrict__ b_q, const float* __restrict__ b_k,
    const float* __restrict__ b_v,
    short* __restrict__ qh, short* __restrict__ kh, short* __restrict__ vht)
{
    if (blockIdx.z == 0)       gemm_mfma_body(qb, Wtq, b_q, qh, 0);
    else if (blockIdx.z == 1)  gemm_mfma_body(kb, Wtk, b_k, kh, 0);
    else                       gemm_mfma_body(vb, Wtv, b_v, vht, 1);
}

__global__ __launch_bounds__(256) void fc_kernel(
    const short* __restrict__ A, const short* __restrict__ Bt,
    const float* __restrict__ bias, float* __restrict__ C)
{
    gemm_mfma_body(A, Bt, bias, C, 2);
}

// ---------------------------------------------------------------------------
// Fused attention: scores(QK^T) + tf-bias + mask + softmax + attn-write + PV.
// Grid (hg=4, ltile=64, b=2) = 512 blocks, 256 thr = 4 waves.
// Block handles 16 l-rows x all 1024 m for head pair {2hg, 2hg+1}.
// tf indices packed once into 64 uint32 regs/thread (layout aligned to the
// MFMA C-layout), reused for both heads.
// ---------------------------------------------------------------------------
__global__ __launch_bounds__(256) void attn_fused_kernel(
    const short* __restrict__ qh, const short* __restrict__ kh,
    const short* __restrict__ vht,
    const int* __restrict__ mask,
    const int* __restrict__ tf1, const int* __restrict__ tf2,
    const int* __restrict__ tf3, const int* __restrict__ tf4,
    const int* __restrict__ tf5,
    const float* __restrict__ emb1, const float* __restrict__ emb2,
    const float* __restrict__ emb3, const float* __restrict__ emb4,
    const float* __restrict__ emb5,
    float* __restrict__ attn, short* __restrict__ pv)
{
    const int hg = blockIdx.x;           // head pair
    const int l0 = blockIdx.y * 16;
    const int b  = blockIdx.z;
    const int t = threadIdx.x, w = t >> 6, lane = t & 63;
    const int lq = lane >> 4, lr = lane & 15;

    __shared__ float s[16 * LP];         // 65.8 KB score/prob tile
    __shared__ float embA[2][5][64];     // emb slices for the 2 heads
    __shared__ float redbuf[2][16][17];  // cross-thread softmax reduce
    __shared__ float rinvs[16];

    // stage emb slices for both heads
    for (int i = t; i < 640; i += 256) {
        int hh = i / 320, rem = i % 320, j = rem >> 6, idx = rem & 63;
        const float* ep = (j == 0) ? emb1 : (j == 1) ? emb2 : (j == 2) ? emb3
                        : (j == 3) ? emb4 : emb5;
        embA[hh][j][idx] = ep[idx * NHEAD + hg * 2 + hh];
    }

    // phase 0: pack tf+mask for this block's 16x1024 positions.
    // lane (w,lq,lr) owns: m = w*256 + mt*16 + lr, row = lq*4 + r
    // bits: [0:6)=i1 [6:12)=i2 [12:18)=i3 [18:24)=i4 [24:30)=i5 [30]=valid [31]=mask
    unsigned packed[16][4];
#pragma unroll
    for (int r = 0; r < 4; ++r) {
        const size_t posb = ((size_t)(b * L_SEQ + l0 + lq * 4 + r)) * L_SEQ + w * 256 + lr;
#pragma unroll
        for (int mt = 0; mt < 16; ++mt) {
            const size_t pos = posb + mt * 16;
            const int t1 = tf1[pos];
            unsigned pk = mask[pos] ? 0x80000000u : 0u;
            if (t1 >= 0) pk |= 0x40000000u | (unsigned)t1;
            pk |= ((unsigned)tf2[pos]) << 6;
            pk |= ((unsigned)tf3[pos]) << 12;
            pk |= ((unsigned)tf4[pos]) << 18;
            pk |= ((unsigned)tf5[pos]) << 24;
            packed[mt][r] = pk;
        }
    }
    __syncthreads();   // embA ready

    const f4 zero = {0.f, 0.f, 0.f, 0.f};

    for (int hh = 0; hh < 2; ++hh) {
        const int h = hg * 2 + hh;
        if (hh) __syncthreads();   // protect s reuse across head iterations

        // ---- QK^T: wave w computes rows l0..l0+15 x m in [w*256, w*256+256)
        const short* qbase = qh + ((size_t)(b * L_SEQ + l0 + lr)) * 512 + h * 64 + lq * 8;
        bf8 a0 = *(const bf8*)(qbase);
        bf8 a1 = *(const bf8*)(qbase + 32);
        f4 acc[16];
#pragma unroll
        for (int mt = 0; mt < 16; ++mt) acc[mt] = zero;
        const short* kbase = kh + ((size_t)(b * L_SEQ + w * 256 + lr)) * 512 + h * 64 + lq * 8;
#pragma unroll
        for (int mt = 0; mt < 16; ++mt) {
            bf8 b0 = *(const bf8*)(kbase + (size_t)mt * 16 * 512);
            bf8 b1 = *(const bf8*)(kbase + (size_t)mt * 16 * 512 + 32);
            acc[mt] = __builtin_amdgcn_mfma_f32_16x16x32_bf16(a0, b0, acc[mt], 0, 0, 0);
            acc[mt] = __builtin_amdgcn_mfma_f32_16x16x32_bf16(a1, b1, acc[mt], 0, 0, 0);
        }

        // ---- bias + mask + scale -> LDS
#pragma unroll
        for (int mt = 0; mt < 16; ++mt) {
#pragma unroll
            for (int r = 0; r < 4; ++r) {
                const unsigned pk = packed[mt][r];
                float bias = 0.f;
                if (pk & 0x40000000u)
                    bias = embA[hh][0][pk & 63] + embA[hh][1][(pk >> 6) & 63]
                         + embA[hh][2][(pk >> 12) & 63] + embA[hh][3][(pk >> 18) & 63]
                         + embA[hh][4][(pk >> 24) & 63];
                float val = (acc[mt][r] + bias) * 0.125f;
                if (pk & 0x80000000u) val = -INFINITY;
                s[(lq * 4 + r) * LP + w * 256 + mt * 16 + lr] = val;
            }
        }
        __syncthreads();

        // ---- softmax: thread t handles row=t&15, cols (t>>4) + 16j
        const int srow = t & 15, cg = t >> 4;
        {
            float mx = -INFINITY;
#pragma unroll 8
            for (int j = 0; j < 64; ++j)
                mx = fmaxf(mx, s[srow * LP + cg + 16 * j]);
            redbuf[0][cg][srow] = mx;
        }
        __syncthreads();
        float M = -INFINITY;
#pragma unroll
        for (int i = 0; i < 16; ++i) M = fmaxf(M, redbuf[0][i][srow]);
        {
            float sm = 0.f;
#pragma unroll 8
            for (int j = 0; j < 64; ++j) {
                const int idx = srow * LP + cg + 16 * j;
                float e = __expf(s[idx] - M);
                s[idx] = e;
                sm += e;
            }
            redbuf[1][cg][srow] = sm;
        }
        __syncthreads();
        {
            float tot = 0.f;
#pragma unroll
            for (int i = 0; i < 16; ++i) tot += redbuf[1][i][srow];
            if (cg == 0) rinvs[srow] = 1.0f / tot;
        }
        __syncthreads();   // rinvs ready; s holds un-normalized e

        // ---- write normalized attn (row j per iteration, fully coalesced)
        float* abase = attn + (((size_t)(h * NB + b)) * L_SEQ + l0) * L_SEQ;
#pragma unroll
        for (int j = 0; j < 16; ++j) {
            const float ri = rinvs[j];
            float4 vv = *(float4*)&s[j * LP + 4 * t];
            vv.x *= ri; vv.y *= ri; vv.z *= ri; vv.w *= ri;
            *(float4*)&abase[(size_t)j * L_SEQ + 4 * t] = vv;
        }

        // ---- PV: wave w computes d-cols [w*16, w*16+16), k over 1024
        f4 pacc = zero;
        const short* vbase = vht + ((size_t)(b * 512 + h * 64 + w * 16 + lr)) * L_SEQ + lq * 8;
        for (int k0 = 0; k0 < L_SEQ; k0 += 32) {
            const float* ap = &s[lr * LP + k0 + lq * 8];
            float4 f0 = *(const float4*)ap;
            float4 f1 = *(const float4*)(ap + 4);
            bf8 af;
            af[0] = f2bf(f0.x); af[1] = f2bf(f0.y); af[2] = f2bf(f0.z); af[3] = f2bf(f0.w);
            af[4] = f2bf(f1.x); af[5] = f2bf(f1.y); af[6] = f2bf(f1.z); af[7] = f2bf(f1.w);
            bf8 bf = *(const bf8*)(vbase + k0);
            pacc = __builtin_amdgcn_mfma_f32_16x16x32_bf16(af, bf, pacc, 0, 0, 0);
        }
#pragma unroll
        for (int r = 0; r < 4; ++r) {
            const int row = lq * 4 + r;
            const float o = pacc[r] * rinvs[row];
            pv[((size_t)(b * L_SEQ + l0 + row)) * 512 + h * 64 + w * 16 + lr] = f2bf(o);
        }
    }
}

// ---------------------------------------------------------------------------
// residual add + LayerNorm, one block per row
// ---------------------------------------------------------------------------
__global__ __launch_bounds__(256) void ln_kernel(
    const float* __restrict__ x, const float* __restrict__ res,
    const float* __restrict__ g, const float* __restrict__ bvec,
    float* __restrict__ out)
{
    const int row = blockIdx.x;
    const int t = threadIdx.x;
    float2 xv = ((const float2*)(x + (size_t)row * DMODEL))[t];
    float2 rv = ((const float2*)(res + (size_t)row * DMODEL))[t];
    const float a = xv.x + rv.x;
    const float c = xv.y + rv.y;
    float s = a + c, sq = a * a + c * c;
#pragma unroll
    for (int off = 32; off; off >>= 1) {
        s  += __shfl_down(s, off);
        sq += __shfl_down(sq, off);
    }
    __shared__ float ssum[4], ssq[4];
    __shared__ float smu, srs;
    const int wid = t >> 6, lane = t & 63;
    if (lane == 0) { ssum[wid] = s; ssq[wid] = sq; }
    __syncthreads();
    if (t == 0) {
        float ts = ssum[0] + ssum[1] + ssum[2] + ssum[3];
        float tq = ssq[0] + ssq[1] + ssq[2] + ssq[3];
        float mu = ts * (1.0f / DMODEL);
        float var = tq * (1.0f / DMODEL) - mu * mu;
        smu = mu;
        srs = rsqrtf(var + 1e-5f);
    }
    __syncthreads();
    const float mu = smu, rs = srs;
    float2 gv = ((const float2*)g)[t];
    float2 bv = ((const float2*)bvec)[t];
    float2 o;
    o.x = (a - mu) * rs * gv.x + bv.x;
    o.y = (c - mu) * rs * gv.y + bv.y;
    ((float2*)(out + (size_t)row * DMODEL))[t] = o;
}

extern "C" void kernel_launch(void* const* d_in, const int* in_sizes, int n_in,
                              void* d_out, int out_size, void* d_ws, size_t ws_size,
                              hipStream_t stream)
{
    const float* q    = (const float*)d_in[0];
    const float* k    = (const float*)d_in[1];
    const float* v    = (const float*)d_in[2];
    const int*   mask = (const int*)d_in[3];
    const int*   tf1  = (const int*)d_in[4];
    const int*   tf2  = (const int*)d_in[5];
    const int*   tf3  = (const int*)d_in[6];
    const int*   tf4  = (const int*)d_in[7];
    const int*   tf5  = (const int*)d_in[8];
    const float* w_q  = (const float*)d_in[9];
    const float* b_q  = (const float*)d_in[10];
    const float* w_k  = (const float*)d_in[11];
    const float* b_k  = (const float*)d_in[12];
    const float* w_v  = (const float*)d_in[13];
    const float* b_v  = (const float*)d_in[14];
    const float* emb1 = (const float*)d_in[15];
    const float* emb2 = (const float*)d_in[16];
    const float* emb3 = (const float*)d_in[17];
    const float* emb4 = (const float*)d_in[18];
    const float* emb5 = (const float*)d_in[19];
    const float* fc_w = (const float*)d_in[20];
    const float* fc_b = (const float*)d_in[21];
    const float* ln_g = (const float*)d_in[22];
    const float* ln_b = (const float*)d_in[23];

    float* out  = (float*)d_out;                       // [2048][512]
    float* attn = out + (size_t)NB * L_SEQ * DMODEL;   // [16][1024][1024]

    char* wsb = (char*)d_ws;
    short* qb   = (short*)(wsb + 0);                    // 2 MiB bf16 [2048][512]
    short* kb   = (short*)(wsb + (2u << 20));
    short* vb   = (short*)(wsb + (4u << 20));
    short* Wtq  = (short*)(wsb + (6u << 20));           // 0.5 MiB each [512n][512k]
    short* Wtk  = (short*)(wsb + (6u << 20) + (512u << 10));
    short* Wtv  = (short*)(wsb + (7u << 20));
    short* Wtfc = (short*)(wsb + (7u << 20) + (512u << 10));
    short* qh   = (short*)(wsb + (8u << 20));           // 2 MiB [2048][512]
    short* kh   = (short*)(wsb + (10u << 20));          // 2 MiB
    short* vht  = (short*)(wsb + (12u << 20));          // 2 MiB [2][512][1024]
    short* pv   = (short*)(wsb + (14u << 20));          // 2 MiB [2048][512]
    float* fco  = (float*)(wsb + (16u << 20));          // 4 MiB [2048][512] fp32

    const int n4 = NB * L_SEQ * DMODEL / 4;             // 262144

    cast3_bf16_kernel<<<dim3(n4 / 256, 3), 256, 0, stream>>>(q, k, v, qb, kb, vb);

    transpose_cast_kernel<<<dim3(16, 16, 4), dim3(32, 8), 0, stream>>>(
        w_q, w_k, w_v, fc_w, Wtq, Wtk, Wtv, Wtfc);

    qkv_proj_kernel<<<dim3(DMODEL / 64, NB * L_SEQ / 64, 3), 256, 0, stream>>>(
        qb, kb, vb, Wtq, Wtk, Wtv, b_q, b_k, b_v, qh, kh, vht);

    attn_fused_kernel<<<dim3(4, 64, 2), 256, 0, stream>>>(
        qh, kh, vht, mask, tf1, tf2, tf3, tf4, tf5,
        emb1, emb2, emb3, emb4, emb5, attn, pv);

    fc_kernel<<<dim3(DMODEL / 64, NB * L_SEQ / 64), 256, 0, stream>>>(
        pv, Wtfc, fc_b, fco);

    ln_kernel<<<NB * L_SEQ, 256, 0, stream>>>(fco, q, ln_g, ln_b, out);
}